// Round 7
// baseline (739.094 us; speedup 1.0000x reference)
//
#include <hip/hip_runtime.h>
#include <math.h>

// ---------------- problem constants ----------------
#define NT 512      // N_TARGET
#define NF 1024     // N_FEAT
#define BATCHSZ 16

// output layout (float elements, concatenated in return order)
constexpr int O_MEM  = 0;          // 16384*512
constexpr int O_TMEM = 8388608;    // 16384 (written as float)
constexpr int O_FEAT = 8404992;    // 16384*1024
constexpr int O_ARE  = 25182208;   // 32*512
constexpr int O_AIM  = 25198592;
constexpr int O_FREQ = 25214976;   // 32
constexpr int O_RP   = 25215008;   // 1536*512
constexpr int O_BIAS = 26001440;   // 512
constexpr int O_FM   = 26001952;   // 1024
constexpr int O_AGR  = 26002976;   // 32*512
constexpr int O_AGI  = 26019360;
constexpr int O_FGR  = 26035744;   // 32
constexpr int O_RPG  = 26035776;   // 1536*512

// ws layout (floats)
constexpr int W_LR    = 0;
constexpr int W_ANORM = 2;     // [2]
constexpr int W_RNORM = 4;     // [2]
constexpr int W_GFR   = 8;     // [2*32]
constexpr int W_TB    = 72;    // [16]
constexpr int W_BAR   = 88;    // [8] grid-barrier counters (uint), zeroed by memsetAsync
constexpr int W_C     = 96;    // [16*32]
constexpr int W_S     = 608;   // [16*32]
constexpr int W_CATZ  = 1120;  // [16*512]
constexpr int W_CATX  = 9312;  // [16*1024]
constexpr int W_GR    = 25696; // [16*512]
constexpr int W_G     = 33888; // [16*512]
constexpr int W_AGRE  = 42080; // [32*512]
constexpr int W_AGIM  = 58464; // [32*512]
constexpr int W_RPART = 74848; // [16*8192] split-K partials (ends 205920)

constexpr float MM_LR = 0.03f;
constexpr float AMP_DECAY = 0.01f;
constexpr float MOM = 0.85f;
constexpr float INV_SQRT_NF = 0.17677669529663687f; // 1/sqrt(32)
constexpr float TWO_PI = 6.283185307179586f;

constexpr long long U_TOTAL = 6295552LL; // float4 units: mem 2097152 + feat 4194304 + tmem 4096
constexpr long long U_SLICE = 786944LL;  // U_TOTAL / 8
constexpr int NB = 256;                  // persistent grid: 1 block/CU always co-resident

__device__ __forceinline__ float sgnf(float x) {
    return (x > 0.f) ? 1.f : ((x < 0.f) ? -1.f : 0.f);
}

__device__ __forceinline__ float wave_reduce(float v) {
#pragma unroll
    for (int o = 32; o > 0; o >>= 1) v += __shfl_down(v, o, 64);
    return v; // lane 0 holds sum
}

// manual one-shot grid barrier; bar[idx] pre-zeroed by hipMemsetAsync
__device__ __forceinline__ void gbar(unsigned int* bar, int idx) {
    __syncthreads();
    if (threadIdx.x == 0) {
        __threadfence();                       // release: my block's writes visible
        atomicAdd(&bar[idx], 1u);
        while (atomicAdd(&bar[idx], 0u) < (unsigned)NB)
            __builtin_amdgcn_s_sleep(2);
    }
    __syncthreads();
    __threadfence();                           // acquire: drop stale cached lines
}

// fetch source value + destination pointer for copy-unit u
__device__ __forceinline__ float4 cp_fetch(long long u, int dsv, int tt,
    const float* __restrict__ x, const float* __restrict__ z,
    const float* __restrict__ memory, const int* __restrict__ t_memory,
    const float* __restrict__ feat_memory, float* __restrict__ out,
    float4** dstp)
{
    if (u < 2097152) {               // memory (row ds <- z)
        int f = (int)u;
        *dstp = (float4*)(out + O_MEM) + f;
        return (f >> 7 == dsv) ? ((const float4*)z)[f & 127]
                               : ((const float4*)memory)[f];
    } else if (u < 6291456) {        // feat_memory (row ds <- x)
        int f = (int)(u - 2097152);
        *dstp = (float4*)(out + O_FEAT) + f;
        return (f >> 8 == dsv) ? ((const float4*)x)[f & 255]
                               : ((const float4*)feat_memory)[f];
    } else {                          // t_memory -> float (row ds <- t)
        int f = (int)(u - 6291456);
        *dstp = (float4*)(out + O_TMEM) + f;
        int4 iv = ((const int4*)t_memory)[f];
        int e = f * 4;
        float4 v;
        v.x = (e + 0 == dsv) ? (float)tt : (float)iv.x;
        v.y = (e + 1 == dsv) ? (float)tt : (float)iv.y;
        v.z = (e + 2 == dsv) ? (float)tt : (float)iv.z;
        v.w = (e + 3 == dsv) ? (float)tt : (float)iv.w;
        return v;
    }
}

// 4-deep unrolled background copy of units [ubase, uend)
__device__ __forceinline__ void copy_units(long long ubase, long long uend,
    int rank, int stride, int dsv, int tt,
    const float* __restrict__ x, const float* __restrict__ z,
    const float* __restrict__ memory, const int* __restrict__ t_memory,
    const float* __restrict__ feat_memory, float* __restrict__ out)
{
    long long u = ubase + rank;
    const long long s1 = stride, s2 = 2LL*stride, s3 = 3LL*stride, s4 = 4LL*stride;
    for (; u + s3 < uend; u += s4) {
        float4 *d0, *d1, *d2, *d3;
        float4 v0 = cp_fetch(u,      dsv, tt, x, z, memory, t_memory, feat_memory, out, &d0);
        float4 v1 = cp_fetch(u + s1, dsv, tt, x, z, memory, t_memory, feat_memory, out, &d1);
        float4 v2 = cp_fetch(u + s2, dsv, tt, x, z, memory, t_memory, feat_memory, out, &d2);
        float4 v3 = cp_fetch(u + s3, dsv, tt, x, z, memory, t_memory, feat_memory, out, &d3);
        *d0 = v0; *d1 = v1; *d2 = v2; *d3 = v3;
    }
    for (; u < uend; u += s1) {
        float4* d;
        float4 v = cp_fetch(u, dsv, tt, x, z, memory, t_memory, feat_memory, out, &d);
        *d = v;
    }
}

// ======== the whole step as one persistent kernel: 256 blocks x 256 ========
__global__ __launch_bounds__(256) void k_all(
    const int* __restrict__ tptr, const int* __restrict__ dsp,
    const int* __restrict__ ts,
    const float* __restrict__ x, const float* __restrict__ z,
    const float* __restrict__ memory, const int* __restrict__ t_memory,
    const float* __restrict__ feat_memory,
    const float* __restrict__ amp_re, const float* __restrict__ amp_im,
    const float* __restrict__ freq, const float* __restrict__ cf,
    const float* __restrict__ res_proj, const float* __restrict__ feat_mean,
    const float* __restrict__ bias,
    const float* __restrict__ amp_grad_re, const float* __restrict__ amp_grad_im,
    const float* __restrict__ freq_grad, const float* __restrict__ res_proj_grad,
    float* __restrict__ out, float* __restrict__ ws)
{
    __shared__ float sh[1024];
    unsigned int* bar = (unsigned int*)(ws + W_BAR);
    const int bb = blockIdx.x, tid = threadIdx.x;
    const int dsv = *dsp;
    const int tt  = *tptr;
    const float nn = (float)(dsv + 1), dd = (float)(dsv + 2);
    const int crank = bb * 256 + tid;       // copy rank
    const int cstride = NB * 256;           // 65536

    for (int b = 0; b < 2; ++b) {
        const float* are_src = b ? out + O_ARE : amp_re;
        const float* aim_src = b ? out + O_AIM : amp_im;
        const float* agr_src = b ? out + O_AGR : amp_grad_re;
        const float* agi_src = b ? out + O_AGI : amp_grad_im;
        const float* fq_src  = b ? out + O_FREQ: freq;
        const float* fgr_src = b ? out + O_FGR : freq_grad;
        const float* rp_src  = b ? out + O_RP  : res_proj;
        const float* rpg_src = b ? out + O_RPG : res_proj_grad;
        const long long s_base = (long long)b * 4 * U_SLICE;
        const int bix = b * 4;              // barrier index base

        // ============ STAGE 1: cat + split-K partials (block=(i,s)) ============
        {
            const int i = bb >> 4, s = bb & 15;
            float* c_l = sh;        // [32]
            float* s_l = sh + 32;   // [32]
            float* cat = sh + 64;   // [96]
            const int bi = ts[b * BATCHSZ + i];
            if (tid < 32) {
                float f  = fq_src[tid];
                float th = tanhf(f);
                float u  = cf[tid] + 2.f * th;
                float sg = 1.f / (1.f + expf(-u));
                float fr = 0.5f * sg;
                float tb = (bi == dsv) ? (float)tt : (float)t_memory[bi];
                float ph = TWO_PI * tb * fr;
                float cv = cosf(ph), sv = sinf(ph);
                c_l[tid] = cv; s_l[tid] = sv;
                if (s == 0) {
                    ws[W_C + i*32 + tid] = cv; ws[W_S + i*32 + tid] = sv;
                    if (tid == 0) ws[W_TB + i] = tb;
                }
            }
            if (bb == 0) {  // per-batch accumulator init
                if (tid == 64) ws[W_ANORM + b] = 0.f;
                if (tid == 65) ws[W_RNORM + b] = 0.f;
                if (tid == 66 && b == 0) ws[W_LR] = (float)pow(0.977, (double)(dsv + 1));
                if (tid >= 96 && tid < 128) ws[W_GFR + b*32 + tid - 96] = 0.f;
            }
            __syncthreads();
            if (tid < 96) {                 // this block's 96-elem cat slice
                int p = s * 96 + tid;
                float cv;
                if (p < NF) {
                    float fmv = (feat_mean[p] * nn + x[p]) / dd;
                    float xv  = (bi == dsv) ? x[p] : feat_memory[bi*NF + p];
                    cv = xv - fmv;
                    ws[W_CATX + i*NF + p] = cv;
                } else {
                    int q = p - NF;
                    float acc = 0.f;
#pragma unroll
                    for (int k = 0; k < 32; ++k)
                        acc += c_l[k] * are_src[k*NT + q] - s_l[k] * aim_src[k*NT + q];
                    cv = acc * INV_SQRT_NF;  // z_ - bias
                    ws[W_CATZ + i*NT + q] = cv;
                }
                cat[tid] = cv;
            }
            __syncthreads();
            const int j = tid;
            const float* rpb = rp_src + (size_t)s * 96 * NT;
            float a0 = 0.f, a1 = 0.f, b0 = 0.f, b1 = 0.f;
#pragma unroll 8
            for (int p = 0; p < 96; p += 2) {
                float c0 = cat[p], c1 = cat[p + 1];
                a0 += c0 * rpb[p*NT + j];
                a1 += c0 * rpb[p*NT + j + 256];
                b0 += c1 * rpb[(p+1)*NT + j];
                b1 += c1 * rpb[(p+1)*NT + j + 256];
            }
            ws[W_RPART + s*8192 + i*NT + j]       = a0 + b0;
            ws[W_RPART + s*8192 + i*NT + j + 256] = a1 + b1;
            copy_units(s_base, s_base + U_SLICE, crank, cstride,
                       dsv, tt, x, z, memory, t_memory, feat_memory, out);
        }
        gbar(bar, bix + 0);

        // ============ STAGE 2: r, g_r, full G (block=(i, jgroup of 32)) ============
        {
            const int i = bb >> 4, jg = bb & 15;
            float* g_sh = sh;        // [512]
            float* d_sh = sh + 512;  // [512]
            const int bi = ts[b * BATCHSZ + i];
#pragma unroll
            for (int ll = 0; ll < 2; ++ll) {
                int l = tid + ll * 256;
                float r = 0.f;
#pragma unroll
                for (int s = 0; s < 16; ++s) r += ws[W_RPART + s*8192 + i*NT + l];
                float bn = (bias[l] * nn + z[l]) / dd;
                float zj = ws[W_CATZ + i*NT + l] + bn;
                float zb = (bi == dsv) ? z[l] : memory[bi*NT + l];
                float s1 = sgnf(zj - zb);
                float ar = fabsf(r) + 1.f;
                float z2 = zj + r / ar;
                float g  = sgnf(z2 - zb) * (MM_LR / 16.f) / (ar * ar);
                g_sh[l] = g; d_sh[l] = s1 * (1.f / 16.f);
                if (jg == 0) {
                    ws[W_GR + i*NT + l] = g;
                    if (b == 0 && i == 0) out[O_BIAS + l] = bn;
                }
            }
            if (b == 0 && jg == 0 && i < 2) {   // fm_new (i=0,1 cover 1024)
#pragma unroll
                for (int ll = 0; ll < 2; ++ll) {
                    int p = i * 512 + tid + ll * 256;
                    out[O_FM + p] = (feat_mean[p] * nn + x[p]) / dd;
                }
            }
            __syncthreads();
            const int w = tid >> 6, lane = tid & 63;
            const float4* g4 = (const float4*)g_sh;
#pragma unroll
            for (int jj = 0; jj < 8; ++jj) {
                int j = jg * 32 + w * 8 + jj;
                const float4* rrow4 = (const float4*)(rp_src + (size_t)(NF + j) * NT);
                float acc = 0.f;
#pragma unroll
                for (int k = 0; k < 2; ++k) {
                    float4 a = rrow4[lane + 64*k];
                    float4 g = g4[lane + 64*k];
                    acc += a.x*g.x + a.y*g.y + a.z*g.z + a.w*g.w;
                }
                acc = wave_reduce(acc);
                if (lane == 0) ws[W_G + i*NT + j] = d_sh[j] + acc;
            }
            copy_units(s_base + U_SLICE, s_base + 2*U_SLICE, crank, cstride,
                       dsv, tt, x, z, memory, t_memory, feat_memory, out);
        }
        gbar(bar, bix + 1);

        // ============ STAGE 3: grads + norms ============
        {
            if (bb < 64) {            // amp grads + anorm
                int e = bb*256 + tid;
                int k = e >> 9;
                float gre = 0.f, gim = 0.f;
#pragma unroll
                for (int i2 = 0; i2 < 16; ++i2) {
                    float G = ws[W_G + i2*NT + (e & 511)];
                    gre += G * ws[W_C + i2*32 + k];
                    gim += G * ws[W_S + i2*32 + k];
                }
                float re = are_src[e], im = aim_src[e];
                float aa = sqrtf(re*re + im*im);
                float dec = AMP_DECAY / (2.f * aa * sqrtf(aa));
                float agr =  gre * INV_SQRT_NF + re * dec;
                float agi = -gim * INV_SQRT_NF + im * dec;
                ws[W_AGRE + e] = agr;
                ws[W_AGIM + e] = agi;
                float v = wave_reduce(agr*agr + agi*agi);
                if ((tid & 63) == 0) atomicAdd(&ws[W_ANORM + b], v);
            } else if (bb < 96) {     // freq-grad partials: 32 blocks x 16 pairs
                int w = tid >> 6, lane = tid & 63;
#pragma unroll
                for (int q = 0; q < 4; ++q) {
                    int pair = (bb - 64)*16 + w*4 + q;   // 512 = 16 i x 32 k
                    int i = pair >> 5, k = pair & 31;
                    float ck = ws[W_C + i*32 + k], sk = ws[W_S + i*32 + k];
                    float acc = 0.f;
#pragma unroll
                    for (int j = lane; j < NT; j += 64)
                        acc += ws[W_G + i*NT + j] * (-sk * are_src[k*NT + j] - ck * aim_src[k*NT + j]);
                    acc = wave_reduce(acc);
                    if (lane == 0)
                        atomicAdd(&ws[W_GFR + b*32 + k], acc * TWO_PI * ws[W_TB + i] * INV_SQRT_NF);
                }
            } else {                  // rg (recomputed in S4) -> rnorm only
                const int rank3 = (bb - 96)*256 + tid;
                const int stride3 = 160*256;
                float v = 0.f;
                for (int e = rank3; e < 786432; e += stride3) {
                    int p = e >> 9, j = e & 511;
                    float rg = 0.f;
#pragma unroll
                    for (int i2 = 0; i2 < 16; ++i2) {
                        float cat = (p < NF) ? ws[W_CATX + i2*NF + p]
                                             : ws[W_CATZ + i2*NT + (p - NF)];
                        rg += cat * ws[W_GR + i2*NT + j];
                    }
                    v += rg * rg;
                }
                v = wave_reduce(v);
                if ((tid & 63) == 0) atomicAdd(&ws[W_RNORM + b], v);
            }
            copy_units(s_base + 2*U_SLICE, s_base + 3*U_SLICE, crank, cstride,
                       dsv, tt, x, z, memory, t_memory, feat_memory, out);
        }
        gbar(bar, bix + 2);

        // ============ STAGE 4: parameter updates ============
        {
            const float lr = ws[W_LR];
            if (bb < 64) {
                int e = bb*256 + tid;
                float anorm = sqrtf(ws[W_ANORM + b]) + 1.f;
                float mr = agr_src[e]*MOM + ws[W_AGRE + e]/anorm;
                out[O_AGR + e] = mr; out[O_ARE + e] = are_src[e] - mr*lr;
                float mi = agi_src[e]*MOM + ws[W_AGIM + e]/anorm;
                out[O_AGI + e] = mi; out[O_AIM + e] = aim_src[e] - mi*lr;
            } else if (bb == 64) {
                if (tid < 64) {
                    float fg = 0.f, th = 0.f;
                    if (tid < 32) {
                        float f = fq_src[tid];
                        th = tanhf(f);
                        float u  = cf[tid] + 2.f*th;
                        float sg = 1.f / (1.f + expf(-u));
                        fg = ws[W_GFR + b*32 + tid] * sg*(1.f-sg)*(1.f-th*th);
                    }
                    float t2 = fg*fg;
#pragma unroll
                    for (int o = 32; o > 0; o >>= 1) t2 += __shfl_down(t2, o, 64);
                    float tot = __shfl(t2, 0, 64);
                    if (tid < 32) {
                        float fnorm = sqrtf(tot) + 1.f;
                        float m = fgr_src[tid]*MOM + fg/fnorm;
                        out[O_FGR + tid] = m;
                        out[O_FREQ + tid] = fq_src[tid] - m*lr;
                    }
                }
            } else {                  // rp update, rg recomputed (identical i2 order)
                const int rank4 = (bb - 65)*256 + tid;
                const int stride4 = 191*256;
                float rnorm = sqrtf(ws[W_RNORM + b]) + 1.f;
                for (int e = rank4; e < 786432; e += stride4) {
                    int p = e >> 9, j = e & 511;
                    float rg = 0.f;
#pragma unroll
                    for (int i2 = 0; i2 < 16; ++i2) {
                        float cat = (p < NF) ? ws[W_CATX + i2*NF + p]
                                             : ws[W_CATZ + i2*NT + (p - NF)];
                        rg += cat * ws[W_GR + i2*NT + j];
                    }
                    float m = rpg_src[e]*MOM + rg/rnorm;
                    out[O_RPG + e] = m; out[O_RP + e] = rp_src[e] - m*lr;
                }
            }
            copy_units(s_base + 3*U_SLICE, s_base + 4*U_SLICE, crank, cstride,
                       dsv, tt, x, z, memory, t_memory, feat_memory, out);
        }
        if (b == 0) gbar(bar, bix + 3);
    }
}

extern "C" void kernel_launch(void* const* d_in, const int* in_sizes, int n_in,
                              void* d_out, int out_size, void* d_ws, size_t ws_size,
                              hipStream_t stream)
{
    const int*   t            = (const int*)d_in[0];
    const int*   dsp          = (const int*)d_in[1];
    const int*   ts           = (const int*)d_in[2];
    const float* x            = (const float*)d_in[3];
    const float* z            = (const float*)d_in[4];
    const float* memory       = (const float*)d_in[5];
    const int*   t_memory     = (const int*)d_in[6];
    const float* feat_memory  = (const float*)d_in[7];
    const float* amp_re       = (const float*)d_in[8];
    const float* amp_im       = (const float*)d_in[9];
    const float* freq         = (const float*)d_in[10];
    const float* cf           = (const float*)d_in[11];
    const float* res_proj     = (const float*)d_in[12];
    const float* feat_mean    = (const float*)d_in[13];
    const float* bias         = (const float*)d_in[14];
    const float* amp_grad_re  = (const float*)d_in[15];
    const float* amp_grad_im  = (const float*)d_in[16];
    const float* freq_grad    = (const float*)d_in[17];
    const float* res_proj_grad= (const float*)d_in[18];
    float* out = (float*)d_out;
    float* ws  = (float*)d_ws;

    // zero the 8 grid-barrier counters (ws floats [88,96))
    hipMemsetAsync((char*)d_ws + W_BAR * sizeof(float), 0, 8 * sizeof(unsigned int), stream);

    k_all<<<NB, 256, 0, stream>>>(t, dsp, ts, x, z, memory, t_memory, feat_memory,
                                  amp_re, amp_im, freq, cf, res_proj, feat_mean, bias,
                                  amp_grad_re, amp_grad_im, freq_grad, res_proj_grad,
                                  out, ws);
}